// Round 10
// baseline (108.141 us; speedup 1.0000x reference)
//
#include <hip/hip_runtime.h>

// out[b,n,m] = sum_d x1[b,n,d] * x2[b,m,d] + const
// B=4, N=M=4096, D=32, fp32 in/out.
//
// R9: R3/R6/R7/R8 (four unrelated structures) all converge at ~3.2-4.0 TB/s
// effective store BW vs 7 TB/s fillBuffer on the same buffer. Discriminator:
// (b) concurrent-stream scatter (1024 resident blocks = 1024 interleaved
//     write streams over 268MB) vs (c) systemic compute+store ceiling.
// This kernel: minimal store path + windowed sweep.
//   - SWAPPED MFMA operands: mfma(A=x2frag, B=x1frag) -> D row dim = m, so
//     each lane's 4 acc regs are 4 consecutive m -> ONE dwordx4 store per
//     MFMA, direct from registers. No LDS, no barriers, no transpose.
//   - Sweep: 512 blocks (2/CU); stripe = it*512 + blockIdx.x -> the GPU
//     writes one 128MB window at a time; each block sweeps its 16-row
//     stripe left->right in 64-col steps (4 waves adjacent).
// Validated maps (R6): A-frag lane->row l&15, k=(l>>4)*8+j; B-frag same with
// col; D: row=(l>>4)*4+r, col=l&15. With swap: D row=m-offset, col=n-offset.

typedef _Float16 half8 __attribute__((ext_vector_type(8)));
typedef float    f32x4 __attribute__((ext_vector_type(4)));

constexpr int Bv = 4;
constexpr int Nv = 4096;
constexpr int Mv = 4096;
constexpr int Dv = 32;
constexpr int NBLK    = 512;                 // 2 blocks/CU
constexpr int STRIPES = Bv * (Nv / 16);      // 1024 stripes of 16 rows

__global__ __launch_bounds__(256)
void pairwise_mfma_sweep(const float* __restrict__ x1,
                         const float* __restrict__ x2,
                         const float* __restrict__ cbias,
                         float* __restrict__ out) {
    const int t    = threadIdx.x;    // 0..255
    const int w    = t >> 6;         // wave 0..3 -> adjacent 16-col group
    const int lane = t & 63;
    const int l16  = lane & 15;
    const int lh   = lane >> 4;      // 0..3
    const float cb = cbias[0];

    for (int it = 0; it < STRIPES / NBLK; ++it) {        // 2 windows
        const int s  = it * NBLK + blockIdx.x;           // stripe id
        const int b  = s >> 8;
        const int n0 = (s & 255) << 4;

        const float* x1b = x1 + (size_t)b * Nv * Dv;
        const float* x2b = x2 + (size_t)b * Mv * Dv;
        float* outb = out + (size_t)b * Nv * Mv;

        // ---- x1 fragment (MFMA B-operand: col = n): lane -> row n0+l16 ----
        const float* pa = x1b + (size_t)(n0 + l16) * Dv + lh * 8;
        const f32x4 a0 = *reinterpret_cast<const f32x4*>(pa);
        const f32x4 a1 = *reinterpret_cast<const f32x4*>(pa + 4);
        half8 nf;
        nf[0] = (_Float16)a0.x; nf[1] = (_Float16)a0.y;
        nf[2] = (_Float16)a0.z; nf[3] = (_Float16)a0.w;
        nf[4] = (_Float16)a1.x; nf[5] = (_Float16)a1.y;
        nf[6] = (_Float16)a1.z; nf[7] = (_Float16)a1.w;

        // per-lane output row base (n fixed per lane = n0 + l16)
        float* orow = outb + (size_t)(n0 + l16) * Mv + lh * 4;

        // ---- m sweep: 64 steps x 64 cols (wave w owns cols mt*64+w*16..+15) ----
        #pragma unroll 4
        for (int mt = 0; mt < Mv / 64; ++mt) {
            const int mbase = mt * 64 + w * 16;

            // x2 fragment (MFMA A-operand: row = m): lane -> row mbase+l16
            const float* pb = x2b + (size_t)(mbase + l16) * Dv + lh * 8;
            const f32x4 b0 = *reinterpret_cast<const f32x4*>(pb);
            const f32x4 b1 = *reinterpret_cast<const f32x4*>(pb + 4);
            half8 mf;
            mf[0] = (_Float16)b0.x; mf[1] = (_Float16)b0.y;
            mf[2] = (_Float16)b0.z; mf[3] = (_Float16)b0.w;
            mf[4] = (_Float16)b1.x; mf[5] = (_Float16)b1.y;
            mf[6] = (_Float16)b1.z; mf[7] = (_Float16)b1.w;

            f32x4 z = {0.f, 0.f, 0.f, 0.f};
            f32x4 acc = __builtin_amdgcn_mfma_f32_16x16x32_f16(mf, nf, z, 0, 0, 0);
            // D: row (lh*4+r) = m offset, col l16 = n offset
            acc.x += cb; acc.y += cb; acc.z += cb; acc.w += cb;
            *reinterpret_cast<f32x4*>(orow + mbase) = acc;   // 4 consecutive m
        }
    }
}

extern "C" void kernel_launch(void* const* d_in, const int* in_sizes, int n_in,
                              void* d_out, int out_size, void* d_ws, size_t ws_size,
                              hipStream_t stream) {
    const float* x1 = (const float*)d_in[0];   // [B,N,D]
    const float* x2 = (const float*)d_in[1];   // [B,M,D]
    const float* cb = (const float*)d_in[2];   // [1]
    float* out = (float*)d_out;                // [B,N,M]

    pairwise_mfma_sweep<<<dim3(NBLK), 256, 0, stream>>>(x1, x2, cb, out);
}